// Round 4
// baseline (221.546 us; speedup 1.0000x reference)
//
#include <hip/hip_runtime.h>

// CREStereo grouped correlation, round 4.
// Round-3 counters: main kernel 114us (VALUBusy 40%, HBM 12%, latency-bound),
// but transpose pre-pass ~100us of the 215us total (scalar 4B accesses, and it
// transposed BOTH tensors). This round:
//  - left transpose ELIMINATED: left staged per-block in LDS (4 pixels/block,
//    thread t loads left[c=t][p0..p0+3] as float4 -> [4][256] LDS tile).
//  - right-only transpose, float4-vectorized both directions via 64x65 tile.
// Main corr kernel unchanged: one wave per (b,pixel), lane = 4 channels,
// wave-uniform bilinear taps as dwordx4, 16-lane shfl_xor group reduction.

namespace {
constexpr int kB = 2;
constexpr int kC = 256;
constexpr int kH = 96;
constexpr int kW = 192;
constexpr int kG = 4;
constexpr int kGC = kC / kG;              // 64
constexpr int kK = 9;
constexpr int kHW = kH * kW;              // 18432
constexpr size_t kPlane = (size_t)kC * kHW;
}

// ---- right-only transpose [C][HW] -> [HW][C], float4 both directions ----
__global__ __launch_bounds__(256) void transpose_right(
    const float* __restrict__ right, float* __restrict__ right_t)
{
  __shared__ float tile[64][65];
  int pt = blockIdx.x;          // pixel tile 0..287
  int ct = blockIdx.y;          // channel tile 0..3
  int b  = blockIdx.z;
  int p0 = pt * 64, c0 = ct * 64;
  const float* inb = right   + (size_t)b * kPlane;
  float*      outb = right_t + (size_t)b * kPlane;
  int t = threadIdx.x;
  int cl = t >> 2;              // 0..63 channel within tile
  int q  = t & 3;
  #pragma unroll
  for (int i = 0; i < 4; ++i) {
    int j = q + 4 * i;          // float4 index 0..15 along pixels
    float4 v = *(const float4*)(inb + (size_t)(c0 + cl) * kHW + p0 + 4 * j);
    tile[cl][4 * j + 0] = v.x;
    tile[cl][4 * j + 1] = v.y;
    tile[cl][4 * j + 2] = v.z;
    tile[cl][4 * j + 3] = v.w;
  }
  __syncthreads();
  int pl = t >> 2;              // 0..63 pixel within tile
  #pragma unroll
  for (int i = 0; i < 4; ++i) {
    int c4 = (t & 3) + 4 * i;   // float4 index 0..15 along channels
    float4 v;
    v.x = tile[4 * c4 + 0][pl];
    v.y = tile[4 * c4 + 1][pl];
    v.z = tile[4 * c4 + 2][pl];
    v.w = tile[4 * c4 + 3][pl];
    *(float4*)(outb + (size_t)(p0 + pl) * kC + c0 + 4 * c4) = v;
  }
}

// ---- main: one wave per (b,pixel); left staged in LDS from original layout ----
__global__ __launch_bounds__(256) void corr_cl_kernel(
    const float* __restrict__ left, const float* __restrict__ right_t,
    const float* __restrict__ flow, const float* __restrict__ extra,
    float* __restrict__ out)
{
  __shared__ float lds_left[4][256];   // [local pixel][channel]
  int p0g = blockIdx.x * 4;            // global pixel index (b*kHW + pix)
  int b   = p0g / kHW;
  int pl0 = p0g % kHW;                 // base pixel within batch (mult of 4)

  {  // cooperative left stage: thread t = channel t, 4 pixels as float4
    int t = threadIdx.x;
    float4 v = *(const float4*)(left + (size_t)b * kPlane + (size_t)t * kHW + pl0);
    lds_left[0][t] = v.x;
    lds_left[1][t] = v.y;
    lds_left[2][t] = v.z;
    lds_left[3][t] = v.w;
  }
  __syncthreads();

  int wv   = threadIdx.x >> 6;         // 0..3: which pixel of the block
  int lane = threadIdx.x & 63;
  int pix  = pl0 + wv;
  int w = pix % kW, h = pix / kW;

  const float4 l4 = ((const float4*)lds_left[wv])[lane];

  const float* flowb = flow + (size_t)b * 2 * kHW + pix;
  float bx = (float)w + flowb[0];
  float by = (float)h + flowb[kHW];
  const float* extb = extra + (size_t)b * 2 * kK * kHW + pix;
  const float* Rb = right_t + (size_t)b * kPlane;

  float res[kK];
  #pragma unroll
  for (int k = 0; k < kK; ++k) {
    float xx = bx + (float)(k - 4) + extb[(size_t)(2 * k) * kHW];
    float yy = by + extb[(size_t)(2 * k + 1) * kHW];
    float xf = floorf(xx), yf = floorf(yy);
    float fx = xx - xf, fy = yy - yf;
    int ix0 = (int)xf, iy0 = (int)yf;
    int ix1 = ix0 + 1, iy1 = iy0 + 1;
    bool vx0 = (ix0 >= 0) && (ix0 < kW);
    bool vx1 = (ix1 >= 0) && (ix1 < kW);
    bool vy0 = (iy0 >= 0) && (iy0 < kH);
    bool vy1 = (iy1 >= 0) && (iy1 < kH);
    int xc0 = min(max(ix0, 0), kW - 1);
    int xc1 = min(max(ix1, 0), kW - 1);
    int yc0 = min(max(iy0, 0), kH - 1);
    int yc1 = min(max(iy1, 0), kH - 1);
    float wx0 = 1.f - fx, wy0 = 1.f - fy;
    float w00 = wx0 * wy0 * ((vx0 && vy0) ? 1.f : 0.f);
    float w01 = fx  * wy0 * ((vx1 && vy0) ? 1.f : 0.f);
    float w10 = wx0 * fy  * ((vx0 && vy1) ? 1.f : 0.f);
    float w11 = fx  * fy  * ((vx1 && vy1) ? 1.f : 0.f);

    float4 t00 = ((const float4*)(Rb + (size_t)(yc0 * kW + xc0) * kC))[lane];
    float4 t01 = ((const float4*)(Rb + (size_t)(yc0 * kW + xc1) * kC))[lane];
    float4 t10 = ((const float4*)(Rb + (size_t)(yc1 * kW + xc0) * kC))[lane];
    float4 t11 = ((const float4*)(Rb + (size_t)(yc1 * kW + xc1) * kC))[lane];

    float sx = w00 * t00.x + w01 * t01.x + w10 * t10.x + w11 * t11.x;
    float sy = w00 * t00.y + w01 * t01.y + w10 * t10.y + w11 * t11.y;
    float sz = w00 * t00.z + w01 * t01.z + w10 * t10.z + w11 * t11.z;
    float sw = w00 * t00.w + w01 * t01.w + w10 * t10.w + w11 * t11.w;
    res[k] = l4.x * sx + l4.y * sy + l4.z * sz + l4.w * sw;
  }

  int g = lane >> 4;
  #pragma unroll
  for (int k = 0; k < kK; ++k) {
    float r = res[k];
    r += __shfl_xor(r, 1);
    r += __shfl_xor(r, 2);
    r += __shfl_xor(r, 4);
    r += __shfl_xor(r, 8);
    if ((lane & 15) == 0)
      out[((size_t)(b * kG + g) * kK + k) * kHW + pix] = r * (1.f / kGC);
  }
}

// ---- fallback (round-2 kernel) if workspace too small ----
__global__ __launch_bounds__(256) void crestereo_corr_fallback(
    const float* __restrict__ left, const float* __restrict__ right,
    const float* __restrict__ flow, const float* __restrict__ extra,
    float* __restrict__ out)
{
  int t = blockIdx.x * blockDim.x + threadIdx.x;
  int w = t % kW;
  int h = (t / kW) % kH;
  int k = (t / kHW) % kK;
  int g = (t / (kHW * kK)) % kG;
  int b = t / (kHW * kK * kG);

  int pix = h * kW + w;
  const float* flowb = flow + b * 2 * kHW + pix;
  float x = (float)(w + (k - 4)) + flowb[0];
  float y = (float)h + flowb[kHW];
  const float* extb = extra + (size_t)(b * 2 * kK + 2 * k) * kHW + pix;
  x += extb[0];
  y += extb[kHW];

  float xf = floorf(x), yf = floorf(y);
  float fx = x - xf, fy = y - yf;
  int ix0 = (int)xf, iy0 = (int)yf;
  int ix1 = ix0 + 1, iy1 = iy0 + 1;
  bool vx0 = (ix0 >= 0) && (ix0 < kW);
  bool vx1 = (ix1 >= 0) && (ix1 < kW);
  bool vy0 = (iy0 >= 0) && (iy0 < kH);
  bool vy1 = (iy1 >= 0) && (iy1 < kH);
  int xc0 = min(max(ix0, 0), kW - 1);
  int xc1 = min(max(ix1, 0), kW - 1);
  int yc0 = min(max(iy0, 0), kH - 1);
  int yc1 = min(max(iy1, 0), kH - 1);
  float wx0 = 1.f - fx, wy0 = 1.f - fy;
  float w00 = wx0 * wy0 * ((vx0 && vy0) ? 1.f : 0.f);
  float w01 = fx  * wy0 * ((vx1 && vy0) ? 1.f : 0.f);
  float w10 = wx0 * fy  * ((vx0 && vy1) ? 1.f : 0.f);
  float w11 = fx  * fy  * ((vx1 && vy1) ? 1.f : 0.f);
  int idx = yc0 * kW + xc0;
  int dx  = xc1 - xc0;
  int dyw = (yc1 - yc0) * kW;

  const float* Rb = right + (size_t)(b * kC + g * kGC) * kHW + idx;
  const float* Lb = left  + (size_t)(b * kC + g * kGC) * kHW + pix;

  float acc = 0.f;
  #pragma unroll 4
  for (int c = 0; c < kGC; ++c) {
    const float* Rc = Rb + (size_t)c * kHW;
    float l   = Lb[(size_t)c * kHW];
    acc += l * (w00 * Rc[0] + w01 * Rc[dx] + w10 * Rc[dyw] + w11 * Rc[dx + dyw]);
  }
  out[(size_t)((b * kG + g) * kK + k) * kHW + pix] = acc * (1.f / kGC);
}

extern "C" void kernel_launch(void* const* d_in, const int* in_sizes, int n_in,
                              void* d_out, int out_size, void* d_ws, size_t ws_size,
                              hipStream_t stream) {
  const float* left  = (const float*)d_in[0];
  const float* right = (const float*)d_in[1];
  const float* flow  = (const float*)d_in[2];
  const float* extra = (const float*)d_in[3];
  float* out = (float*)d_out;

  size_t need = (size_t)kB * kPlane * sizeof(float);  // ~37.7 MB (right_t only)
  if (ws_size >= need) {
    float* right_t = (float*)d_ws;
    dim3 tgrid(kHW / 64, kC / 64, kB);   // 288 x 4 x 2
    transpose_right<<<tgrid, 256, 0, stream>>>(right, right_t);
    int blocks = kB * kHW / 4;           // 9216 blocks, 4 pixels each
    corr_cl_kernel<<<blocks, 256, 0, stream>>>(left, right_t, flow, extra, out);
  } else {
    int total = kB * kG * kK * kH * kW;
    crestereo_corr_fallback<<<(total + 255) / 256, 256, 0, stream>>>(
        left, right, flow, extra, out);
  }
}

// Round 5
// 209.221 us; speedup vs baseline: 1.0589x; 1.0589x over previous
//
#include <hip/hip_runtime.h>

// CREStereo grouped correlation, round 5.
// History: R3 = channels-last f32 (main 114us, transpose ~25us, +74us fixed
// harness overhead). R4's LDS left-staging regressed (stride-73KB loads ->
// FETCH 229MB). R5: back to transposing BOTH tensors, now to FP16
// channels-last, and the main kernel uses v_dot2_f32_f16 (f32 accumulate).
// Taps drop 16B->8B per lane (halves L1/L2 bytes + VGPR pressure) and the
// per-k math drops from ~40 f32 FMAs to 8 fdot2 + 4 FMAs.

namespace {
constexpr int kB = 2;
constexpr int kC = 256;
constexpr int kH = 96;
constexpr int kW = 192;
constexpr int kG = 4;
constexpr int kGC = kC / kG;              // 64
constexpr int kK = 9;
constexpr int kHW = kH * kW;              // 18432
constexpr size_t kPlane = (size_t)kC * kHW;
}

typedef _Float16 half4_t __attribute__((ext_vector_type(4)));
typedef _Float16 half2_t __attribute__((ext_vector_type(2)));

__device__ __forceinline__ float dot4h(half4_t t, half2_t l0, half2_t l1) {
#if __has_builtin(__builtin_amdgcn_fdot2)
  float r = __builtin_amdgcn_fdot2(__builtin_shufflevector(t, t, 0, 1), l0, 0.f, false);
  return  __builtin_amdgcn_fdot2(__builtin_shufflevector(t, t, 2, 3), l1, r, false);
#else
  return (float)t[0] * (float)l0[0] + (float)t[1] * (float)l0[1] +
         (float)t[2] * (float)l1[0] + (float)t[3] * (float)l1[1];
#endif
}

// ---- transpose [C][HW] f32 -> [HW][C] fp16, both tensors (z = b*2+tensor) ----
__global__ __launch_bounds__(256) void transpose_fp16(
    const float* __restrict__ left, const float* __restrict__ right,
    _Float16* __restrict__ left_t, _Float16* __restrict__ right_t)
{
  __shared__ float tile[64][65];
  int pt = blockIdx.x;          // pixel tile 0..287
  int ct = blockIdx.y;          // channel tile 0..3
  int z  = blockIdx.z;
  int b  = z >> 1;
  const float* in = (z & 1) ? right : left;
  _Float16*   dst = (z & 1) ? right_t : left_t;
  int p0 = pt * 64, c0 = ct * 64;
  const float* inb = in + (size_t)b * kPlane;
  _Float16*   outb = dst + (size_t)b * kPlane;
  int t = threadIdx.x;
  int cl = t >> 2;              // channel within tile
  int q  = t & 3;
  #pragma unroll
  for (int i = 0; i < 4; ++i) {
    int j = q + 4 * i;          // float4 index along pixels
    float4 v = *(const float4*)(inb + (size_t)(c0 + cl) * kHW + p0 + 4 * j);
    tile[cl][4 * j + 0] = v.x;
    tile[cl][4 * j + 1] = v.y;
    tile[cl][4 * j + 2] = v.z;
    tile[cl][4 * j + 3] = v.w;
  }
  __syncthreads();
  int pl = t >> 2;              // pixel within tile
  #pragma unroll
  for (int i = 0; i < 4; ++i) {
    int c4 = (t & 3) + 4 * i;   // half4 index along channels
    half4_t hv;
    hv[0] = (_Float16)tile[4 * c4 + 0][pl];
    hv[1] = (_Float16)tile[4 * c4 + 1][pl];
    hv[2] = (_Float16)tile[4 * c4 + 2][pl];
    hv[3] = (_Float16)tile[4 * c4 + 3][pl];
    *(half4_t*)(outb + (size_t)(p0 + pl) * kC + c0 + 4 * c4) = hv;
  }
}

// ---- main: one wave per (b,pixel); lane owns 4 channels (half4 = 8B) ----
__global__ __launch_bounds__(256) void corr_fp16_kernel(
    const _Float16* __restrict__ left_t, const _Float16* __restrict__ right_t,
    const float* __restrict__ flow, const float* __restrict__ extra,
    float* __restrict__ out)
{
  int wave = blockIdx.x * 4 + (threadIdx.x >> 6);
  int lane = threadIdx.x & 63;
  int pix = wave % kHW;
  int b   = wave / kHW;
  int w = pix % kW, h = pix / kW;

  const half4_t l4 = ((const half4_t*)(left_t + ((size_t)b * kHW + pix) * kC))[lane];
  const half2_t l0 = __builtin_shufflevector(l4, l4, 0, 1);
  const half2_t l1 = __builtin_shufflevector(l4, l4, 2, 3);

  const float* flowb = flow + (size_t)b * 2 * kHW + pix;
  float bx = (float)w + flowb[0];
  float by = (float)h + flowb[kHW];
  const float* extb = extra + (size_t)b * 2 * kK * kHW + pix;
  const _Float16* Rb = right_t + (size_t)b * kPlane;

  float res[kK];
  #pragma unroll
  for (int k = 0; k < kK; ++k) {
    float xx = bx + (float)(k - 4) + extb[(size_t)(2 * k) * kHW];
    float yy = by + extb[(size_t)(2 * k + 1) * kHW];
    float xf = floorf(xx), yf = floorf(yy);
    float fx = xx - xf, fy = yy - yf;
    int ix0 = (int)xf, iy0 = (int)yf;
    int ix1 = ix0 + 1, iy1 = iy0 + 1;
    bool vx0 = (ix0 >= 0) && (ix0 < kW);
    bool vx1 = (ix1 >= 0) && (ix1 < kW);
    bool vy0 = (iy0 >= 0) && (iy0 < kH);
    bool vy1 = (iy1 >= 0) && (iy1 < kH);
    int xc0 = min(max(ix0, 0), kW - 1);
    int xc1 = min(max(ix1, 0), kW - 1);
    int yc0 = min(max(iy0, 0), kH - 1);
    int yc1 = min(max(iy1, 0), kH - 1);
    float wx0 = 1.f - fx, wy0 = 1.f - fy;
    float w00 = wx0 * wy0 * ((vx0 && vy0) ? 1.f : 0.f);
    float w01 = fx  * wy0 * ((vx1 && vy0) ? 1.f : 0.f);
    float w10 = wx0 * fy  * ((vx0 && vy1) ? 1.f : 0.f);
    float w11 = fx  * fy  * ((vx1 && vy1) ? 1.f : 0.f);

    half4_t t00 = ((const half4_t*)(Rb + (size_t)(yc0 * kW + xc0) * kC))[lane];
    half4_t t01 = ((const half4_t*)(Rb + (size_t)(yc0 * kW + xc1) * kC))[lane];
    half4_t t10 = ((const half4_t*)(Rb + (size_t)(yc1 * kW + xc0) * kC))[lane];
    half4_t t11 = ((const half4_t*)(Rb + (size_t)(yc1 * kW + xc1) * kC))[lane];

    float d00 = dot4h(t00, l0, l1);
    float d01 = dot4h(t01, l0, l1);
    float d10 = dot4h(t10, l0, l1);
    float d11 = dot4h(t11, l0, l1);
    res[k] = w00 * d00 + w01 * d01 + w10 * d10 + w11 * d11;
  }

  int g = lane >> 4;
  #pragma unroll
  for (int k = 0; k < kK; ++k) {
    float r = res[k];
    r += __shfl_xor(r, 1);
    r += __shfl_xor(r, 2);
    r += __shfl_xor(r, 4);
    r += __shfl_xor(r, 8);
    if ((lane & 15) == 0)
      out[((size_t)(b * kG + g) * kK + k) * kHW + pix] = r * (1.f / kGC);
  }
}

// ---- fallback (round-2 kernel) if workspace too small ----
__global__ __launch_bounds__(256) void crestereo_corr_fallback(
    const float* __restrict__ left, const float* __restrict__ right,
    const float* __restrict__ flow, const float* __restrict__ extra,
    float* __restrict__ out)
{
  int t = blockIdx.x * blockDim.x + threadIdx.x;
  int w = t % kW;
  int h = (t / kW) % kH;
  int k = (t / kHW) % kK;
  int g = (t / (kHW * kK)) % kG;
  int b = t / (kHW * kK * kG);

  int pix = h * kW + w;
  const float* flowb = flow + b * 2 * kHW + pix;
  float x = (float)(w + (k - 4)) + flowb[0];
  float y = (float)h + flowb[kHW];
  const float* extb = extra + (size_t)(b * 2 * kK + 2 * k) * kHW + pix;
  x += extb[0];
  y += extb[kHW];

  float xf = floorf(x), yf = floorf(y);
  float fx = x - xf, fy = y - yf;
  int ix0 = (int)xf, iy0 = (int)yf;
  int ix1 = ix0 + 1, iy1 = iy0 + 1;
  bool vx0 = (ix0 >= 0) && (ix0 < kW);
  bool vx1 = (ix1 >= 0) && (ix1 < kW);
  bool vy0 = (iy0 >= 0) && (iy0 < kH);
  bool vy1 = (iy1 >= 0) && (iy1 < kH);
  int xc0 = min(max(ix0, 0), kW - 1);
  int xc1 = min(max(ix1, 0), kW - 1);
  int yc0 = min(max(iy0, 0), kH - 1);
  int yc1 = min(max(iy1, 0), kH - 1);
  float wx0 = 1.f - fx, wy0 = 1.f - fy;
  float w00 = wx0 * wy0 * ((vx0 && vy0) ? 1.f : 0.f);
  float w01 = fx  * wy0 * ((vx1 && vy0) ? 1.f : 0.f);
  float w10 = wx0 * fy  * ((vx0 && vy1) ? 1.f : 0.f);
  float w11 = fx  * fy  * ((vx1 && vy1) ? 1.f : 0.f);
  int idx = yc0 * kW + xc0;
  int dx  = xc1 - xc0;
  int dyw = (yc1 - yc0) * kW;

  const float* Rb = right + (size_t)(b * kC + g * kGC) * kHW + idx;
  const float* Lb = left  + (size_t)(b * kC + g * kGC) * kHW + pix;

  float acc = 0.f;
  #pragma unroll 4
  for (int c = 0; c < kGC; ++c) {
    const float* Rc = Rb + (size_t)c * kHW;
    float l   = Lb[(size_t)c * kHW];
    acc += l * (w00 * Rc[0] + w01 * Rc[dx] + w10 * Rc[dyw] + w11 * Rc[dx + dyw]);
  }
  out[(size_t)((b * kG + g) * kK + k) * kHW + pix] = acc * (1.f / kGC);
}

extern "C" void kernel_launch(void* const* d_in, const int* in_sizes, int n_in,
                              void* d_out, int out_size, void* d_ws, size_t ws_size,
                              hipStream_t stream) {
  const float* left  = (const float*)d_in[0];
  const float* right = (const float*)d_in[1];
  const float* flow  = (const float*)d_in[2];
  const float* extra = (const float*)d_in[3];
  float* out = (float*)d_out;

  size_t need = 2 * (size_t)kB * kPlane * sizeof(_Float16);  // ~37.7 MB
  if (ws_size >= need) {
    _Float16* left_t  = (_Float16*)d_ws;
    _Float16* right_t = left_t + (size_t)kB * kPlane;
    dim3 tgrid(kHW / 64, kC / 64, kB * 2);   // 288 x 4 x 4
    transpose_fp16<<<tgrid, 256, 0, stream>>>(left, right, left_t, right_t);
    int blocks = kB * kHW / 4;               // 9216 blocks, 4 pixel-waves each
    corr_fp16_kernel<<<blocks, 256, 0, stream>>>(left_t, right_t, flow, extra, out);
  } else {
    int total = kB * kG * kK * kH * kW;
    crestereo_corr_fallback<<<(total + 255) / 256, 256, 0, stream>>>(
        left, right, flow, extra, out);
  }
}

// Round 6
// 169.801 us; speedup vs baseline: 1.3047x; 1.2322x over previous
//
#include <hip/hip_runtime.h>

// CREStereo grouped correlation, round 6.
// R5 post-mortem: main kernel is per-wave-instruction bound, not byte bound
// (halving tap bytes moved dur only 9%; VALUBusy 40%, occ 21%). The ~360-VALU
// coordinate/weight block was computed redundantly by all 64 lanes for ONE
// pixel. R6 lane layout: wave = 4 pixels x 16 lanes, lane owns 16 channels
// (2x half8 = 2x dwordx4 per tap). Coord math now serves 4 pixels per wave
// (4x amortization); VMEM instrs per pixel drop 2.4x; group reduce = 2 shfls.

namespace {
constexpr int kB = 2;
constexpr int kC = 256;
constexpr int kH = 96;
constexpr int kW = 192;
constexpr int kG = 4;
constexpr int kGC = kC / kG;              // 64
constexpr int kK = 9;
constexpr int kHW = kH * kW;              // 18432
constexpr size_t kPlane = (size_t)kC * kHW;
}

typedef _Float16 half8_t __attribute__((ext_vector_type(8)));
typedef _Float16 half4_t __attribute__((ext_vector_type(4)));
typedef _Float16 half2_t __attribute__((ext_vector_type(2)));

__device__ __forceinline__ float dot8(half8_t a, half8_t b, float acc) {
#if __has_builtin(__builtin_amdgcn_fdot2)
  #pragma unroll
  for (int i = 0; i < 4; ++i) {
    half2_t a2 = {a[2 * i], a[2 * i + 1]};
    half2_t b2 = {b[2 * i], b[2 * i + 1]};
    acc = __builtin_amdgcn_fdot2(a2, b2, acc, false);
  }
#else
  #pragma unroll
  for (int i = 0; i < 8; ++i) acc += (float)a[i] * (float)b[i];
#endif
  return acc;
}

// ---- transpose [C][HW] f32 -> [HW][C] fp16, both tensors (z = b*2+tensor) ----
__global__ __launch_bounds__(256) void transpose_fp16(
    const float* __restrict__ left, const float* __restrict__ right,
    _Float16* __restrict__ left_t, _Float16* __restrict__ right_t)
{
  __shared__ float tile[64][65];
  int pt = blockIdx.x;          // pixel tile 0..287
  int ct = blockIdx.y;          // channel tile 0..3
  int z  = blockIdx.z;
  int b  = z >> 1;
  const float* in = (z & 1) ? right : left;
  _Float16*   dst = (z & 1) ? right_t : left_t;
  int p0 = pt * 64, c0 = ct * 64;
  const float* inb = in + (size_t)b * kPlane;
  _Float16*   outb = dst + (size_t)b * kPlane;
  int t = threadIdx.x;
  int cl = t >> 2;              // channel within tile
  int q  = t & 3;
  #pragma unroll
  for (int i = 0; i < 4; ++i) {
    int j = q + 4 * i;          // float4 index along pixels
    float4 v = *(const float4*)(inb + (size_t)(c0 + cl) * kHW + p0 + 4 * j);
    tile[cl][4 * j + 0] = v.x;
    tile[cl][4 * j + 1] = v.y;
    tile[cl][4 * j + 2] = v.z;
    tile[cl][4 * j + 3] = v.w;
  }
  __syncthreads();
  int pl = t >> 2;              // pixel within tile
  #pragma unroll
  for (int i = 0; i < 4; ++i) {
    int c4 = (t & 3) + 4 * i;   // half4 index along channels
    half4_t hv;
    hv[0] = (_Float16)tile[4 * c4 + 0][pl];
    hv[1] = (_Float16)tile[4 * c4 + 1][pl];
    hv[2] = (_Float16)tile[4 * c4 + 2][pl];
    hv[3] = (_Float16)tile[4 * c4 + 3][pl];
    *(half4_t*)(outb + (size_t)(p0 + pl) * kC + c0 + 4 * c4) = hv;
  }
}

// ---- main: wave = 4 pixels x 16 lanes; lane owns 16 channels ----
__global__ __launch_bounds__(256) void corr_fp16_kernel(
    const _Float16* __restrict__ left_t, const _Float16* __restrict__ right_t,
    const float* __restrict__ flow, const float* __restrict__ extra,
    float* __restrict__ out)
{
  int gw   = blockIdx.x * 4 + (threadIdx.x >> 6);  // global wave id
  int lane = threadIdx.x & 63;
  int base = gw * 4;            // first of 4 pixels (global, b-major)
  int b    = base / kHW;
  int pl0  = base % kHW;        // kHW % 4 == 0: no wave straddles b
  int p    = lane >> 4;         // pixel cluster 0..3
  int cl   = lane & 15;         // channel-lane: owns channels cl*16..cl*16+15
  int pix  = pl0 + p;
  int w = pix % kW, h = pix / kW;

  const _Float16* Lp = left_t + ((size_t)b * kHW + pix) * kC + cl * 16;
  half8_t lA = *(const half8_t*)(Lp);
  half8_t lB = *(const half8_t*)(Lp + 8);

  const float* flowb = flow + (size_t)b * 2 * kHW + pix;
  float bx = (float)w + flowb[0];
  float by = (float)h + flowb[kHW];
  const float* extb = extra + (size_t)b * 2 * kK * kHW + pix;
  const _Float16* Rb = right_t + (size_t)b * kPlane + cl * 16;

  float res[kK];
  #pragma unroll
  for (int k = 0; k < kK; ++k) {
    float xx = bx + (float)(k - 4) + extb[(size_t)(2 * k) * kHW];
    float yy = by + extb[(size_t)(2 * k + 1) * kHW];
    float xf = floorf(xx), yf = floorf(yy);
    float fx = xx - xf, fy = yy - yf;
    int ix0 = (int)xf, iy0 = (int)yf;
    int ix1 = ix0 + 1, iy1 = iy0 + 1;
    bool vx0 = (ix0 >= 0) && (ix0 < kW);
    bool vx1 = (ix1 >= 0) && (ix1 < kW);
    bool vy0 = (iy0 >= 0) && (iy0 < kH);
    bool vy1 = (iy1 >= 0) && (iy1 < kH);
    int xc0 = min(max(ix0, 0), kW - 1);
    int xc1 = min(max(ix1, 0), kW - 1);
    int yc0 = min(max(iy0, 0), kH - 1);
    int yc1 = min(max(iy1, 0), kH - 1);
    float wx0 = 1.f - fx, wy0 = 1.f - fy;
    float w00 = wx0 * wy0 * ((vx0 && vy0) ? 1.f : 0.f);
    float w01 = fx  * wy0 * ((vx1 && vy0) ? 1.f : 0.f);
    float w10 = wx0 * fy  * ((vx0 && vy1) ? 1.f : 0.f);
    float w11 = fx  * fy  * ((vx1 && vy1) ? 1.f : 0.f);

    const _Float16* R00 = Rb + (size_t)(yc0 * kW + xc0) * kC;
    const _Float16* R01 = Rb + (size_t)(yc0 * kW + xc1) * kC;
    const _Float16* R10 = Rb + (size_t)(yc1 * kW + xc0) * kC;
    const _Float16* R11 = Rb + (size_t)(yc1 * kW + xc1) * kC;
    half8_t a00 = *(const half8_t*)(R00), b00 = *(const half8_t*)(R00 + 8);
    half8_t a01 = *(const half8_t*)(R01), b01 = *(const half8_t*)(R01 + 8);
    half8_t a10 = *(const half8_t*)(R10), b10 = *(const half8_t*)(R10 + 8);
    half8_t a11 = *(const half8_t*)(R11), b11 = *(const half8_t*)(R11 + 8);

    float d00 = dot8(b00, lB, dot8(a00, lA, 0.f));
    float d01 = dot8(b01, lB, dot8(a01, lA, 0.f));
    float d10 = dot8(b10, lB, dot8(a10, lA, 0.f));
    float d11 = dot8(b11, lB, dot8(a11, lA, 0.f));
    res[k] = w00 * d00 + w01 * d01 + w10 * d10 + w11 * d11;
  }

  // group = 4 adjacent channel-lanes (64 ch); reduce across lanes cl%4
  int g = cl >> 2;
  #pragma unroll
  for (int k = 0; k < kK; ++k) {
    float r = res[k];
    r += __shfl_xor(r, 1);
    r += __shfl_xor(r, 2);
    if ((cl & 3) == 0)
      out[((size_t)(b * kG + g) * kK + k) * kHW + pix] = r * (1.f / kGC);
  }
}

// ---- fallback (round-2 kernel) if workspace too small ----
__global__ __launch_bounds__(256) void crestereo_corr_fallback(
    const float* __restrict__ left, const float* __restrict__ right,
    const float* __restrict__ flow, const float* __restrict__ extra,
    float* __restrict__ out)
{
  int t = blockIdx.x * blockDim.x + threadIdx.x;
  int w = t % kW;
  int h = (t / kW) % kH;
  int k = (t / kHW) % kK;
  int g = (t / (kHW * kK)) % kG;
  int b = t / (kHW * kK * kG);

  int pix = h * kW + w;
  const float* flowb = flow + b * 2 * kHW + pix;
  float x = (float)(w + (k - 4)) + flowb[0];
  float y = (float)h + flowb[kHW];
  const float* extb = extra + (size_t)(b * 2 * kK + 2 * k) * kHW + pix;
  x += extb[0];
  y += extb[kHW];

  float xf = floorf(x), yf = floorf(y);
  float fx = x - xf, fy = y - yf;
  int ix0 = (int)xf, iy0 = (int)yf;
  int ix1 = ix0 + 1, iy1 = iy0 + 1;
  bool vx0 = (ix0 >= 0) && (ix0 < kW);
  bool vx1 = (ix1 >= 0) && (ix1 < kW);
  bool vy0 = (iy0 >= 0) && (iy0 < kH);
  bool vy1 = (iy1 >= 0) && (iy1 < kH);
  int xc0 = min(max(ix0, 0), kW - 1);
  int xc1 = min(max(ix1, 0), kW - 1);
  int yc0 = min(max(iy0, 0), kH - 1);
  int yc1 = min(max(iy1, 0), kH - 1);
  float wx0 = 1.f - fx, wy0 = 1.f - fy;
  float w00 = wx0 * wy0 * ((vx0 && vy0) ? 1.f : 0.f);
  float w01 = fx  * wy0 * ((vx1 && vy0) ? 1.f : 0.f);
  float w10 = wx0 * fy  * ((vx0 && vy1) ? 1.f : 0.f);
  float w11 = fx  * fy  * ((vx1 && vy1) ? 1.f : 0.f);
  int idx = yc0 * kW + xc0;
  int dx  = xc1 - xc0;
  int dyw = (yc1 - yc0) * kW;

  const float* Rb = right + (size_t)(b * kC + g * kGC) * kHW + idx;
  const float* Lb = left  + (size_t)(b * kC + g * kGC) * kHW + pix;

  float acc = 0.f;
  #pragma unroll 4
  for (int c = 0; c < kGC; ++c) {
    const float* Rc = Rb + (size_t)c * kHW;
    float l   = Lb[(size_t)c * kHW];
    acc += l * (w00 * Rc[0] + w01 * Rc[dx] + w10 * Rc[dyw] + w11 * Rc[dx + dyw]);
  }
  out[(size_t)((b * kG + g) * kK + k) * kHW + pix] = acc * (1.f / kGC);
}

extern "C" void kernel_launch(void* const* d_in, const int* in_sizes, int n_in,
                              void* d_out, int out_size, void* d_ws, size_t ws_size,
                              hipStream_t stream) {
  const float* left  = (const float*)d_in[0];
  const float* right = (const float*)d_in[1];
  const float* flow  = (const float*)d_in[2];
  const float* extra = (const float*)d_in[3];
  float* out = (float*)d_out;

  size_t need = 2 * (size_t)kB * kPlane * sizeof(_Float16);  // ~37.7 MB
  if (ws_size >= need) {
    _Float16* left_t  = (_Float16*)d_ws;
    _Float16* right_t = left_t + (size_t)kB * kPlane;
    dim3 tgrid(kHW / 64, kC / 64, kB * 2);   // 288 x 4 x 4
    transpose_fp16<<<tgrid, 256, 0, stream>>>(left, right, left_t, right_t);
    int waves = kB * kHW / 4;                // 9216 waves, 4 pixels each
    corr_fp16_kernel<<<waves / 4, 256, 0, stream>>>(left_t, right_t, flow, extra, out);
  } else {
    int total = kB * kG * kK * kH * kW;
    crestereo_corr_fallback<<<(total + 255) / 256, 256, 0, stream>>>(
        left, right, flow, extra, out);
  }
}